// Round 7
// baseline (600.309 us; speedup 1.0000x reference)
//
#include <hip/hip_runtime.h>
#include <hip/hip_bf16.h>
#include <cstdint>

// Problem: W [1024, 8192], x [8192, 1024], b [1024]; idx=0..4095, idx_comp=4096..8191
// cont path = x @ (Wc@Wc^T) = x @ G (G [1024,1024]).
// 3 kernels + 128B memset (barrier counters + amax scalars):
//   K1 prep (512 blocks, grid-barrier): W-quant->Wq,WqT | Wc cast->Wcb |
//      amax_x (atomicMax) -- bar -- xq fake-quant + xbf cast.
//   K2 gemm1 (512 blocks, grid-barrier): blocks<64: G=Wcb@Wcb^T (128x128,K=4096);
//      blocks>=64: 4-5 tiles of Hexp=xq@Wq (+ amax_h atomicMax) -- bar --
//      each block quantizes ITS OWN Hexp tiles in place (block-local re-read:
//      coherent by construction; only the amax scalar crosses the barrier).
//   K3 gemm2 (512 blocks): out = relu(Hq@Wq^T + xbf@G + b), round-3 verbatim.
// Safety rule (from round-6 failure): across an in-kernel grid barrier, the only
// cross-block data is a scalar via device-scope atomic RMW + atomic load. Bulk
// data crosses kernel boundaries only. 512-block co-residency at
// launch_bounds(256,2)/32KB LDS was empirically confirmed in round 6.

using bf16x8 = __attribute__((ext_vector_type(8))) __bf16;
using f32x4  = __attribute__((ext_vector_type(4))) float;

typedef const __attribute__((address_space(1))) void g_void;
typedef __attribute__((address_space(3))) void l_void;

__device__ __forceinline__ void gload16(const void* g, void* l) {
  __builtin_amdgcn_global_load_lds((g_void*)g, (l_void*)l, 16, 0, 0);
}

__device__ __forceinline__ ushort f2bf(float f) {
  union { float f; unsigned u; } c; c.f = f;
  unsigned r = c.u + 0x7FFFu + ((c.u >> 16) & 1u);  // RNE truncate
  return (ushort)(r >> 16);
}
__device__ __forceinline__ float bf2f(ushort u) {
  union { unsigned u; float f; } c; c.u = ((unsigned)u) << 16;
  return c.f;
}

__device__ __forceinline__ void gridbar(unsigned* cnt) {
  __syncthreads();
  if (threadIdx.x == 0) {
    __threadfence();
    __hip_atomic_fetch_add(cnt, 1u, __ATOMIC_ACQ_REL, __HIP_MEMORY_SCOPE_AGENT);
    while (__hip_atomic_load(cnt, __ATOMIC_ACQUIRE, __HIP_MEMORY_SCOPE_AGENT) <
           512u)
      __builtin_amdgcn_s_sleep(2);
  }
  __syncthreads();
}

// ---- round-3 verified staged K-loop (16x16x32 MFMA, T2 chunk swizzle) ----
template <int STRIDE>
__device__ __forceinline__ void kloop(const ushort* Ag, const ushort* Bg,
                                      int kbeg, int kend, ushort* As, ushort* Bs,
                                      f32x4 (&acc)[4][4], int wm, int wn,
                                      int l15, int quad, int sel) {
  const int tid = threadIdx.x;
  ushort* Asl0 = As + tid * 8;        ushort* Asl1 = As + 4096 + tid * 8;
  ushort* Bsl0 = Bs + tid * 8;        ushort* Bsl1 = Bs + 4096 + tid * 8;
  for (int k0 = kbeg; k0 < kend; k0 += 64) {
    __syncthreads();
    gload16(Ag + k0, Asl0);
    gload16(Ag + (size_t)64 * STRIDE + k0, Asl0 + 64 * 32);
    gload16(Bg + k0, Bsl0);
    gload16(Bg + (size_t)64 * STRIDE + k0, Bsl0 + 64 * 32);
    gload16(Ag + k0 + 32, Asl1);
    gload16(Ag + (size_t)64 * STRIDE + k0 + 32, Asl1 + 64 * 32);
    gload16(Bg + k0 + 32, Bsl1);
    gload16(Bg + (size_t)64 * STRIDE + k0 + 32, Bsl1 + 64 * 32);
    __syncthreads();
    #pragma unroll
    for (int p = 0; p < 2; ++p) {
      bf16x8 af[4], bfr[4];
      #pragma unroll
      for (int i = 0; i < 4; ++i)
        af[i] = *(const bf16x8*)&As[p * 4096 + (wm + i * 16 + l15) * 32 + sel];
      #pragma unroll
      for (int j = 0; j < 4; ++j)
        bfr[j] = *(const bf16x8*)&Bs[p * 4096 + (wn + j * 16 + l15) * 32 + sel];
      #pragma unroll
      for (int i = 0; i < 4; ++i)
        #pragma unroll
        for (int j = 0; j < 4; ++j)
          acc[i][j] = __builtin_amdgcn_mfma_f32_16x16x32_bf16(af[i], bfr[j],
                                                              acc[i][j], 0, 0, 0);
    }
  }
}

// ============ K1: prep (W-quant | Wc cast | amax_x -- bar -- xq/xbf) ============
__global__ __launch_bounds__(256, 2) void prep_kernel(
    const float* __restrict__ W, const float4* __restrict__ x,
    ushort* __restrict__ Wq, ushort* __restrict__ WqT,
    ushort* __restrict__ Wcb, unsigned* __restrict__ bar,
    unsigned* __restrict__ amaxx,
    uint4* __restrict__ xq, uint4* __restrict__ xbf) {
  __shared__ __align__(16) ushort tile[64][72];
  __shared__ float sred[4];
  const int b = blockIdx.x;
  const int tid = threadIdx.x;
  const int lane = tid & 63, wave = tid >> 6;

  // ---- (a) two 64x64 W-quant tiles (round-3 body, t = b*2+tt) ----
  #pragma unroll 1
  for (int tt = 0; tt < 2; ++tt) {
    const int t = b * 2 + tt;
    const int rt = t >> 6, ct = t & 63;
    const int r0 = rt * 64, c0 = ct * 64;
    const int e = tid & 31, hw = tid >> 5;
    #pragma unroll
    for (int it = 0; it < 16; ++it) {
      const int g = it * 8 + hw;
      const int row = g >> 1;
      const int cg = (g & 1) * 32;
      const float w = W[(size_t)(r0 + row) * 8192 + c0 + cg + e];
      float aw = fabsf(w);
      float m = aw;
      #pragma unroll
      for (int d = 1; d <= 16; d <<= 1) m = fmaxf(m, __shfl_xor(m, d));
      int idx = (aw == m) ? e : 32;
      #pragma unroll
      for (int d = 1; d <= 16; d <<= 1) idx = min(idx, __shfl_xor(idx, d));
      const int i1 = idx;
      float a2 = (e == i1) ? -1.f : aw;
      float m2 = a2;
      #pragma unroll
      for (int d = 1; d <= 16; d <<= 1) m2 = fmaxf(m2, __shfl_xor(m2, d));
      int idx2 = (a2 == m2) ? e : 32;
      #pragma unroll
      for (int d = 1; d <= 16; d <<= 1) idx2 = min(idx2, __shfl_xor(idx2, d));
      const int i2 = idx2;

      const float scale = fmaxf(m, 1e-8f);
      const float nb = w / scale;
      float q;
      if (e == i1 || e == i2) {
        q = rintf(nb * 7.f) / 7.f;
      } else {
        float s = (nb > 0.f) ? 1.f : ((nb < 0.f) ? -1.f : 0.f);
        q = s * ((fabsf(nb) > 0.66f) ? 1.f : (1.f / 3.f));
      }
      const ushort qb = f2bf(q * scale);
      Wq[(size_t)(r0 + row) * 4096 + c0 + cg + e] = qb;
      tile[cg + e][row] = qb;
    }
    __syncthreads();
    const int c = tid >> 2;
    const int q4 = (tid & 3) * 16;
    uint4 v0 = *(const uint4*)&tile[c][q4];
    uint4 v1 = *(const uint4*)&tile[c][q4 + 8];
    *(uint4*)(WqT + (size_t)(c0 + c) * 1024 + r0 + q4) = v0;
    *(uint4*)(WqT + (size_t)(c0 + c) * 1024 + r0 + q4 + 8) = v1;
    __syncthreads();
  }

  // ---- (b) cast W[:,4096:] -> Wcb ----
  for (int u = b * 256 + tid; u < 1024 * 1024; u += 512 * 256) {
    const int row = u >> 10;
    const int c4 = u & 1023;
    float4 v = *(const float4*)(W + (size_t)row * 8192 + 4096 + c4 * 4);
    ushort4 o;
    o.x = f2bf(v.x); o.y = f2bf(v.y); o.z = f2bf(v.z); o.w = f2bf(v.w);
    *(ushort4*)(Wcb + (size_t)row * 4096 + c4 * 4) = o;
  }

  // ---- (c) amax(|x|) -> atomicMax (device-scope RMW: coherence-safe) ----
  {
    float m = 0.f;
    for (int i = b * 256 + tid; i < 8192 * 1024 / 4; i += 512 * 256) {
      float4 v = x[i];
      m = fmaxf(m, fmaxf(fmaxf(fabsf(v.x), fabsf(v.y)),
                         fmaxf(fabsf(v.z), fabsf(v.w))));
    }
    #pragma unroll
    for (int off = 32; off > 0; off >>= 1) m = fmaxf(m, __shfl_down(m, off));
    if (lane == 0) sred[wave] = m;
    __syncthreads();
    if (tid == 0) {
      float r = fmaxf(fmaxf(sred[0], sred[1]), fmaxf(sred[2], sred[3]));
      atomicMax(amaxx, __float_as_uint(r));
    }
  }
  gridbar(&bar[0]);

  // ---- (d) xq fake-quant + xbf cast (round-3 prep_x body) ----
  const float amax = fmaxf(
      __uint_as_float(__hip_atomic_load(amaxx, __ATOMIC_ACQUIRE,
                                        __HIP_MEMORY_SCOPE_AGENT)),
      1e-8f);
  const float scale = 127.f / amax;
  for (int i = b * 256 + tid; i < 8192 * 1024 / 8; i += 512 * 256) {
    float4 a = x[i * 2], v2 = x[i * 2 + 1];
    float v[8] = {a.x, a.y, a.z, a.w, v2.x, v2.y, v2.z, v2.w};
    unsigned qw[4], bw[4];
    #pragma unroll
    for (int j = 0; j < 4; ++j) {
      float q0 = fminf(fmaxf(rintf(v[2 * j] * scale), -128.f), 127.f) / scale;
      float q1 = fminf(fmaxf(rintf(v[2 * j + 1] * scale), -128.f), 127.f) / scale;
      qw[j] = (unsigned)f2bf(q0) | ((unsigned)f2bf(q1) << 16);
      bw[j] = (unsigned)f2bf(v[2 * j]) | ((unsigned)f2bf(v[2 * j + 1]) << 16);
    }
    xq[i] = make_uint4(qw[0], qw[1], qw[2], qw[3]);
    xbf[i] = make_uint4(bw[0], bw[1], bw[2], bw[3]);
  }
}

// ============ K2: G (blocks<64) | gemm1 4-5 tiles/block -- bar -- own-tile quant ============
__global__ __launch_bounds__(256, 2) void gemm1_kernel(
    const ushort* __restrict__ Wcb, ushort* __restrict__ G,
    const ushort* __restrict__ Aq, const ushort* __restrict__ BT,
    ushort* __restrict__ Hexp, unsigned* __restrict__ bar,
    unsigned* __restrict__ amaxh) {
  __shared__ __align__(16) ushort As[8192];
  __shared__ __align__(16) ushort Bs[8192];
  __shared__ float sred[4];
  const int b = blockIdx.x;
  const int tid = threadIdx.x;
  const int lane = tid & 63, wave = tid >> 6;
  const int l15 = lane & 15, quad = lane >> 4;
  const int wm = (wave >> 1) << 6, wn = (wave & 1) << 6;
  const int sel = (quad ^ ((l15 >> 1) & 3)) * 8;        // read-side swizzle
  const int scs = ((tid & 3) ^ ((tid >> 3) & 3)) * 8;   // stage-side swizzle

  if (b < 64) {
    // ---- G tile: 128x128, K=4096 (round-3 verbatim) ----
    const int gy = b >> 3, gx = b & 7;
    const int i0 = gy * 128, j0 = gx * 128;
    f32x4 acc[4][4];
    #pragma unroll
    for (int i = 0; i < 4; ++i)
      #pragma unroll
      for (int j = 0; j < 4; ++j) acc[i][j] = (f32x4){0.f, 0.f, 0.f, 0.f};
    const ushort* Ag = Wcb + (size_t)(i0 + (tid >> 2)) * 4096 + scs;
    const ushort* Bg = Wcb + (size_t)(j0 + (tid >> 2)) * 4096 + scs;
    kloop<4096>(Ag, Bg, 0, 4096, As, Bs, acc, wm, wn, l15, quad, sel);
    const int row0 = i0 + wm + quad * 4;
    const int col0 = j0 + wn + l15;
    #pragma unroll
    for (int i = 0; i < 4; ++i)
      #pragma unroll
      for (int j = 0; j < 4; ++j)
        #pragma unroll
        for (int r = 0; r < 4; ++r)
          G[(size_t)(row0 + i * 16 + r) * 1024 + (col0 + j * 16)] =
              f2bf(acc[i][j][r]);
    gridbar(&bar[1]);
    return;
  }

  // ---- gemm1: 4-5 tiles per block (tiles t = iB + k*448; 448%8==0 keeps the
  //      tile's XCD field == block's XCD residue) ----
  const int iB = b - 64;
  const int ntiles = (iB < 256) ? 5 : 4;
  float lmax = 0.f;
  #pragma unroll 1
  for (int k = 0; k < ntiles; ++k) {
    const int t = iB + k * 448;
    const int xcd = t & 7;
    const int s = t >> 3;
    const int tt = (xcd << 2) | (s >> 6);
    const int uu = s & 63;
    const int bx = ((tt & 3) << 3) | (uu & 7);
    const int by = ((tt >> 2) << 3) | (uu >> 3);
    f32x4 acc[4][4];
    #pragma unroll
    for (int i = 0; i < 4; ++i)
      #pragma unroll
      for (int j = 0; j < 4; ++j) acc[i][j] = (f32x4){0.f, 0.f, 0.f, 0.f};
    const ushort* Ag = Aq + (size_t)(by * 128 + (tid >> 2)) * 1024 + scs;
    const ushort* Bg = BT + (size_t)(bx * 128 + (tid >> 2)) * 1024 + scs;
    kloop<1024>(Ag, Bg, 0, 1024, As, Bs, acc, wm, wn, l15, quad, sel);
    const int row0 = by * 128 + wm + quad * 4;
    const int col0 = bx * 128 + wn + l15;
    #pragma unroll
    for (int i = 0; i < 4; ++i)
      #pragma unroll
      for (int j = 0; j < 4; ++j)
        #pragma unroll
        for (int r = 0; r < 4; ++r) {
          float v = acc[i][j][r];
          lmax = fmaxf(lmax, fabsf(v));
          Hexp[(size_t)(row0 + i * 16 + r) * 4096 + (col0 + j * 16)] = f2bf(v);
        }
  }
  #pragma unroll
  for (int off = 32; off > 0; off >>= 1)
    lmax = fmaxf(lmax, __shfl_down(lmax, off));
  if (lane == 0) sred[wave] = lmax;
  __syncthreads();
  if (tid == 0) {
    float m = fmaxf(fmaxf(sred[0], sred[1]), fmaxf(sred[2], sred[3]));
    atomicMax(amaxh, __float_as_uint(m));
  }
  gridbar(&bar[1]);

  // ---- quantize OWN tiles in place (reads this block's own writes; quant
  //      arithmetic byte-identical to round-3's quant_h) ----
  const float amax = fmaxf(
      __uint_as_float(__hip_atomic_load(amaxh, __ATOMIC_ACQUIRE,
                                        __HIP_MEMORY_SCOPE_AGENT)),
      1e-8f);
  const float scale = 127.f / amax;
  #pragma unroll 1
  for (int k = 0; k < ntiles; ++k) {
    const int t = iB + k * 448;
    const int xcd = t & 7;
    const int s = t >> 3;
    const int tt = (xcd << 2) | (s >> 6);
    const int uu = s & 63;
    const int bx = ((tt & 3) << 3) | (uu & 7);
    const int by = ((tt >> 2) << 3) | (uu >> 3);
    for (int q = tid; q < 2048; q += 256) {       // 128 rows x 16 uint4
      const int row = q >> 4, c16 = q & 15;
      uint4* p = (uint4*)(Hexp + (size_t)(by * 128 + row) * 4096 + bx * 128 +
                          c16 * 8);
      uint4 a = *p;
      unsigned w[4] = {a.x, a.y, a.z, a.w};
      #pragma unroll
      for (int j = 0; j < 4; ++j) {
        float lo = bf2f((ushort)(w[j] & 0xFFFF));
        float hi = bf2f((ushort)(w[j] >> 16));
        lo = fminf(fmaxf(rintf(lo * scale), -128.f), 127.f) / scale;
        hi = fminf(fmaxf(rintf(hi * scale), -128.f), 127.f) / scale;
        w[j] = (unsigned)f2bf(lo) | ((unsigned)f2bf(hi) << 16);
      }
      *p = make_uint4(w[0], w[1], w[2], w[3]);
    }
  }
}

// ============ K3: gemm2 (round-3 verbatim) ============
__global__ __launch_bounds__(256, 2) void gemm2_kernel(
    const ushort* __restrict__ Hq, const ushort* __restrict__ Wq,
    const ushort* __restrict__ Xb, const ushort* __restrict__ G,
    const float* __restrict__ bias, float* __restrict__ out) {
  __shared__ __align__(16) ushort As[8192];
  __shared__ __align__(16) ushort Bs[8192];

  const int l = blockIdx.x;
  const int xcd = l & 7;
  const int s = l >> 3;
  const int by = (xcd << 3) | (s >> 3);
  const int bx = s & 7;

  const int tid = threadIdx.x;
  const int lane = tid & 63, wave = tid >> 6;
  const int wm = (wave >> 1) << 6, wn = (wave & 1) << 6;
  const int l15 = lane & 15, quad = lane >> 4;
  const int sel = (quad ^ ((l15 >> 1) & 3)) * 8;
  const int scs = ((tid & 3) ^ ((tid >> 3) & 3)) * 8;

  f32x4 acc[4][4];
  #pragma unroll
  for (int i = 0; i < 4; ++i)
    #pragma unroll
    for (int j = 0; j < 4; ++j) acc[i][j] = (f32x4){0.f, 0.f, 0.f, 0.f};

  {
    const ushort* Ag = Hq + (size_t)(by * 128 + (tid >> 2)) * 4096 + scs;
    const ushort* Bg = Wq + (size_t)(bx * 128 + (tid >> 2)) * 4096 + scs;
    kloop<4096>(Ag, Bg, 0, 4096, As, Bs, acc, wm, wn, l15, quad, sel);
  }
  {
    const ushort* Ag = Xb + (size_t)(by * 128 + (tid >> 2)) * 1024 + scs;
    const ushort* Bg = G + (size_t)(bx * 128 + (tid >> 2)) * 1024 + scs;
    kloop<1024>(Ag, Bg, 0, 1024, As, Bs, acc, wm, wn, l15, quad, sel);
  }

  const int row0 = by * 128 + wm + quad * 4;
  const int col0 = bx * 128 + wn + l15;
  #pragma unroll
  for (int i = 0; i < 4; ++i)
    #pragma unroll
    for (int j = 0; j < 4; ++j) {
      float bv = bias[col0 + j * 16];
      #pragma unroll
      for (int r = 0; r < 4; ++r) {
        float v = acc[i][j][r] + bv;
        v = fmaxf(v, 0.f);
        out[(size_t)(row0 + i * 16 + r) * 1024 + (col0 + j * 16)] = v;
      }
    }
}

extern "C" void kernel_launch(void* const* d_in, const int* in_sizes, int n_in,
                              void* d_out, int out_size, void* d_ws, size_t ws_size,
                              hipStream_t stream) {
  (void)in_sizes; (void)n_in; (void)out_size; (void)ws_size;
  const float* x = (const float*)d_in[0];   // [8192,1024]
  const float* W = (const float*)d_in[1];   // [1024,8192]
  const float* b = (const float*)d_in[2];   // [1024]

  char* ws = (char*)d_ws;
  unsigned* bar   = (unsigned*)ws;                     // [0..15], memset 0
  unsigned* amaxh = (unsigned*)(ws + 64);              // memset 0
  unsigned* amaxx = (unsigned*)(ws + 72);              // memset 0
  ushort* xq   = (ushort*)(ws + 16384);                // 16 MB [8192,1024]
  ushort* xbf  = xq   + (size_t)8192 * 1024;           // 16 MB [8192,1024]
  ushort* Wq   = xbf  + (size_t)8192 * 1024;           //  8 MB [1024,4096]
  ushort* WqT  = Wq   + (size_t)1024 * 4096;           //  8 MB [4096,1024]
  ushort* Wcb  = WqT  + (size_t)4096 * 1024;           //  8 MB [1024,4096]
  ushort* G    = Wcb  + (size_t)1024 * 4096;           //  2 MB [1024,1024]
  ushort* Hexp = G    + (size_t)1024 * 1024;           // 64 MB [8192,4096]

  hipMemsetAsync(ws, 0, 128, stream);  // zero barrier counters + amax scalars
  prep_kernel<<<512, 256, 0, stream>>>(W, (const float4*)x, Wq, WqT, Wcb, bar,
                                       amaxx, (uint4*)xq, (uint4*)xbf);
  gemm1_kernel<<<512, 256, 0, stream>>>(Wcb, G, xq, WqT, Hexp, bar, amaxh);
  gemm2_kernel<<<512, 256, 0, stream>>>(Hexp, Wq, xbf, G, b, (float*)d_out);
}

// Round 8
// 326.151 us; speedup vs baseline: 1.8406x; 1.8406x over previous
//
#include <hip/hip_runtime.h>
#include <hip/hip_bf16.h>
#include <cstdint>

// Problem constants: W [N=1024, M=8192], x [B=8192, N=1024], b [1024]
// idx = 0..4095 (quantized cols), idx_comp = 4096..8191 (continuous cols)
//
// cont path = x @ (Wc@Wc^T) = x @ G, G [1024,1024] symmetric.
// DAG (all bf16 MFMA, 16x16x32):
//   L1: prep_wa: W-quant+transpose -> Wq,WqT | Wc cast -> Wcb | amax_x slots
//       (+ zeroes amax_h scalar; cross-kernel boundary => coherent)
//   L2: prep_x: reduce amax_x slots, write xq (fake-quant) + xbf (cast)
//   L3: G = Wcb@Wcb^T (128x128 tiles, blocks<64) | gemm1: Hexp = xq@Wq + amax_h
//   L4: quant_h in place
//   L5: gemm2: out = relu(Hq@Wq^T + xbf@G + b)   (split-K: 4096 + 1024)
//
// Round-8: round-3 proven structure (341.5 us; gemm2 95.6 us, bank-conflicts 0)
// + slot-amax (verified rounds 4/5): kills the memset launch. Nothing else.
// Closed axes (measured): phase-scheduled GEMM (r1/r2), LUT quant fusion (r4),
// 32x32 MFMA w/ this swizzle (r5), grid-barrier fusion (r6 coherence / r7
// barrier cost ~150us).

using bf16x8 = __attribute__((ext_vector_type(8))) __bf16;
using f32x4  = __attribute__((ext_vector_type(4))) float;

typedef const __attribute__((address_space(1))) void g_void;
typedef __attribute__((address_space(3))) void l_void;

__device__ __forceinline__ void gload16(const void* g, void* l) {
  __builtin_amdgcn_global_load_lds((g_void*)g, (l_void*)l, 16, 0, 0);
}

__device__ __forceinline__ ushort f2bf(float f) {
  union { float f; unsigned u; } c; c.f = f;
  unsigned r = c.u + 0x7FFFu + ((c.u >> 16) & 1u);  // RNE truncate
  return (ushort)(r >> 16);
}
__device__ __forceinline__ float bf2f(ushort u) {
  union { unsigned u; float f; } c; c.u = ((unsigned)u) << 16;
  return c.f;
}

// ============ L1: W quant+transpose (blocks <1024) | Wc cast (<5120) | amax_x ============
__global__ void prep_wa_kernel(const float* __restrict__ W,
                               const float4* __restrict__ x,
                               ushort* __restrict__ Wq,
                               ushort* __restrict__ WqT,
                               ushort* __restrict__ Wcb,
                               unsigned* __restrict__ scal) {
  const int bidx = blockIdx.x;
  const int tid = threadIdx.x;

  if (bidx < 1024) {
    // ---- quantize a 64x64 tile of W[:, :4096]; write Wq + WqT (LDS transpose) ----
    __shared__ __align__(16) ushort tile[64][72];  // [col][row], pad 72: rows 16B-aligned
    const int rt = bidx >> 6;         // 16 row tiles (1024/64)
    const int ct = bidx & 63;         // 64 col tiles (4096/64)
    const int r0 = rt * 64, c0 = ct * 64;
    const int e = tid & 31;           // element within 32-quant-block
    const int hw = tid >> 5;          // half-wave id 0..7
    #pragma unroll
    for (int it = 0; it < 16; ++it) {
      const int g = it * 8 + hw;      // 0..127 quant-groups in tile
      const int row = g >> 1;
      const int cg = (g & 1) * 32;
      const float w = W[(size_t)(r0 + row) * 8192 + c0 + cg + e];
      float aw = fabsf(w);
      float m = aw;
      #pragma unroll
      for (int d = 1; d <= 16; d <<= 1) m = fmaxf(m, __shfl_xor(m, d));
      int idx = (aw == m) ? e : 32;
      #pragma unroll
      for (int d = 1; d <= 16; d <<= 1) idx = min(idx, __shfl_xor(idx, d));
      const int i1 = idx;
      float a2 = (e == i1) ? -1.f : aw;
      float m2 = a2;
      #pragma unroll
      for (int d = 1; d <= 16; d <<= 1) m2 = fmaxf(m2, __shfl_xor(m2, d));
      int idx2 = (a2 == m2) ? e : 32;
      #pragma unroll
      for (int d = 1; d <= 16; d <<= 1) idx2 = min(idx2, __shfl_xor(idx2, d));
      const int i2 = idx2;

      const float scale = fmaxf(m, 1e-8f);
      const float nb = w / scale;
      float q;
      if (e == i1 || e == i2) {
        q = rintf(nb * 7.f) / 7.f;
      } else {
        float s = (nb > 0.f) ? 1.f : ((nb < 0.f) ? -1.f : 0.f);
        q = s * ((fabsf(nb) > 0.66f) ? 1.f : (1.f / 3.f));
      }
      const ushort qb = f2bf(q * scale);
      Wq[(size_t)(r0 + row) * 4096 + c0 + cg + e] = qb;
      tile[cg + e][row] = qb;
    }
    __syncthreads();
    // transposed write: WqT row (c0+c) gets tile[c][0..64) at offset r0
    const int c = tid >> 2;
    const int q4 = (tid & 3) * 16;
    uint4 v0 = *(const uint4*)&tile[c][q4];
    uint4 v1 = *(const uint4*)&tile[c][q4 + 8];
    *(uint4*)(WqT + (size_t)(c0 + c) * 1024 + r0 + q4) = v0;
    *(uint4*)(WqT + (size_t)(c0 + c) * 1024 + r0 + q4 + 8) = v1;
  } else if (bidx < 5120) {
    // ---- cast W[:, 4096:] to bf16 -> Wcb [1024,4096] ----
    const int u = (bidx - 1024) * 256 + tid;   // 0 .. 1024*1024-1
    const int row = u >> 10;
    const int c4 = u & 1023;
    float4 v = *(const float4*)(W + (size_t)row * 8192 + 4096 + c4 * 4);
    ushort4 o;
    o.x = f2bf(v.x); o.y = f2bf(v.y); o.z = f2bf(v.z); o.w = f2bf(v.w);
    *(ushort4*)(Wcb + (size_t)row * 4096 + c4 * 4) = o;
  } else {
    // ---- amax(|x|): per-block max -> slot array (full write, poison-safe) ----
    float m = 0.f;
    const int base = (bidx - 5120) * 256 + tid;
    const int stride = 2048 * 256;
    for (int i = base; i < 8192 * 1024 / 4; i += stride) {
      float4 v = x[i];
      m = fmaxf(m, fmaxf(fmaxf(fabsf(v.x), fabsf(v.y)),
                         fmaxf(fabsf(v.z), fabsf(v.w))));
    }
    #pragma unroll
    for (int off = 32; off > 0; off >>= 1) m = fmaxf(m, __shfl_down(m, off));
    __shared__ float wm[4];
    int lane = tid & 63, wave = tid >> 6;
    if (lane == 0) wm[wave] = m;
    __syncthreads();
    if (tid == 0) {
      float r = fmaxf(fmaxf(wm[0], wm[1]), fmaxf(wm[2], wm[3]));
      ((float*)(scal + 16))[bidx - 5120] = r;
      if (bidx == 5120) scal[1] = 0u;   // zero amax_h (gemm1 runs after boundary)
    }
  }
}

// ============ L2: prep_x (slot-reduce amax, xq fake-quant + xbf cast) ============
__global__ void prep_x_kernel(const float4* __restrict__ x,
                              const float* __restrict__ slots,
                              uint4* __restrict__ xq, uint4* __restrict__ xbf) {
  __shared__ float red[4];
  float mm = 0.f;
  for (int i = threadIdx.x; i < 2048; i += 256) mm = fmaxf(mm, slots[i]);
  #pragma unroll
  for (int off = 32; off > 0; off >>= 1) mm = fmaxf(mm, __shfl_down(mm, off));
  if ((threadIdx.x & 63) == 0) red[threadIdx.x >> 6] = mm;
  __syncthreads();
  const float amax = fmaxf(fmaxf(fmaxf(red[0], red[1]), fmaxf(red[2], red[3])),
                           1e-8f);
  const float scale = 127.f / amax;
  const int base = blockIdx.x * 256 + threadIdx.x;
  const int stride = 2048 * 256;
  const int n8 = 8192 * 1024 / 8;
  for (int i = base; i < n8; i += stride) {
    float4 a = x[i * 2], b = x[i * 2 + 1];
    float v[8] = {a.x, a.y, a.z, a.w, b.x, b.y, b.z, b.w};
    unsigned qw[4], bw[4];
    #pragma unroll
    for (int j = 0; j < 4; ++j) {
      float q0 = fminf(fmaxf(rintf(v[2 * j] * scale), -128.f), 127.f) / scale;
      float q1 = fminf(fmaxf(rintf(v[2 * j + 1] * scale), -128.f), 127.f) / scale;
      qw[j] = (unsigned)f2bf(q0) | ((unsigned)f2bf(q1) << 16);
      bw[j] = (unsigned)f2bf(v[2 * j]) | ((unsigned)f2bf(v[2 * j + 1]) << 16);
    }
    xq[i] = make_uint4(qw[0], qw[1], qw[2], qw[3]);
    xbf[i] = make_uint4(bw[0], bw[1], bw[2], bw[3]);
  }
}

// ============ L3: G-GEMM 128x128 tiles (blocks <64) | gemm1 ============
// G[i,j] = sum_m Wcb[i,m]*Wcb[j,m] — gemm2-loop1-style staging, stride 4096.
__global__ __launch_bounds__(256, 2) void gemm1_kernel(
    const ushort* __restrict__ Wcb,
    ushort* __restrict__ G,
    const ushort* __restrict__ Aq, const ushort* __restrict__ BT,
    ushort* __restrict__ Hexp, unsigned* __restrict__ amax_bits) {
  __shared__ __align__(16) ushort As[2][128 * 32];
  __shared__ __align__(16) ushort Bs[2][128 * 32];
  __shared__ float wredmax[4];

  const int bidx = blockIdx.x;
  const int tid = threadIdx.x;
  const int lane = tid & 63, wave = tid >> 6;
  const int l15 = lane & 15, quad = lane >> 4;
  const int wm = (wave >> 1) << 6, wn = (wave & 1) << 6;
  // T2 chunk swizzle: LDS[row][chunk] holds global chunk (chunk ^ ((row>>1)&3)).
  const int sel = (quad ^ ((l15 >> 1) & 3)) * 8;        // read-side
  const int scs = ((tid & 3) ^ ((tid >> 3) & 3)) * 8;   // stage-side

  ushort* Asl0 = As[0] + tid * 8; ushort* Asl1 = As[1] + tid * 8;
  ushort* Bsl0 = Bs[0] + tid * 8; ushort* Bsl1 = Bs[1] + tid * 8;

  f32x4 acc[4][4];
  #pragma unroll
  for (int i = 0; i < 4; ++i)
    #pragma unroll
    for (int j = 0; j < 4; ++j) acc[i][j] = (f32x4){0.f, 0.f, 0.f, 0.f};

  if (bidx < 64) {
    // ---- G-GEMM: 128x128 tile per block, K=4096 ----
    const int gy = bidx >> 3, gx = bidx & 7;
    const int i0 = gy * 128, j0 = gx * 128;
    const ushort* Ag = Wcb + (size_t)(i0 + (tid >> 2)) * 4096 + scs;
    const ushort* Bg = Wcb + (size_t)(j0 + (tid >> 2)) * 4096 + scs;
    for (int k0 = 0; k0 < 4096; k0 += 64) {
      __syncthreads();
      gload16(Ag + k0, Asl0);
      gload16(Ag + (size_t)64 * 4096 + k0, Asl0 + 64 * 32);
      gload16(Bg + k0, Bsl0);
      gload16(Bg + (size_t)64 * 4096 + k0, Bsl0 + 64 * 32);
      gload16(Ag + k0 + 32, Asl1);
      gload16(Ag + (size_t)64 * 4096 + k0 + 32, Asl1 + 64 * 32);
      gload16(Bg + k0 + 32, Bsl1);
      gload16(Bg + (size_t)64 * 4096 + k0 + 32, Bsl1 + 64 * 32);
      __syncthreads();
      #pragma unroll
      for (int p = 0; p < 2; ++p) {
        bf16x8 af[4], bfr[4];
        #pragma unroll
        for (int i = 0; i < 4; ++i)
          af[i] = *(const bf16x8*)&As[p][(wm + i * 16 + l15) * 32 + sel];
        #pragma unroll
        for (int j = 0; j < 4; ++j)
          bfr[j] = *(const bf16x8*)&Bs[p][(wn + j * 16 + l15) * 32 + sel];
        #pragma unroll
        for (int i = 0; i < 4; ++i)
          #pragma unroll
          for (int j = 0; j < 4; ++j)
            acc[i][j] = __builtin_amdgcn_mfma_f32_16x16x32_bf16(af[i], bfr[j], acc[i][j], 0, 0, 0);
      }
    }
    const int row0 = i0 + wm + quad * 4;
    const int col0 = j0 + wn + l15;
    #pragma unroll
    for (int i = 0; i < 4; ++i)
      #pragma unroll
      for (int j = 0; j < 4; ++j)
        #pragma unroll
        for (int r = 0; r < 4; ++r)
          G[(size_t)(row0 + i * 16 + r) * 1024 + (col0 + j * 16)] = f2bf(acc[i][j][r]);
    return;
  }

  // ---- gemm1: Hexp[8192,4096] = xq @ Wq (2048 blocks, l = bidx-64) ----
  // 64 % 8 == 0 so l%8 still matches the HW XCD round-robin.
  const int l = bidx - 64;
  const int xcd = l & 7;
  const int s = l >> 3;                     // 0..255
  const int t = (xcd << 2) | (s >> 6);      // 0..31
  const int u = s & 63;
  const int bx = ((t & 3) << 3) | (u & 7);  // 0..31
  const int by = ((t >> 2) << 3) | (u >> 3);// 0..63

  const ushort* Ag = Aq + (size_t)(by * 128 + (tid >> 2)) * 1024 + scs;
  const ushort* Bg = BT + (size_t)(bx * 128 + (tid >> 2)) * 1024 + scs;

  for (int k0 = 0; k0 < 1024; k0 += 64) {
    __syncthreads();
    gload16(Ag + k0, Asl0);
    gload16(Ag + 64 * 1024 + k0, Asl0 + 64 * 32);
    gload16(Bg + k0, Bsl0);
    gload16(Bg + 64 * 1024 + k0, Bsl0 + 64 * 32);
    gload16(Ag + k0 + 32, Asl1);
    gload16(Ag + 64 * 1024 + k0 + 32, Asl1 + 64 * 32);
    gload16(Bg + k0 + 32, Bsl1);
    gload16(Bg + 64 * 1024 + k0 + 32, Bsl1 + 64 * 32);
    __syncthreads();

    #pragma unroll
    for (int p = 0; p < 2; ++p) {
      bf16x8 af[4], bfr[4];
      #pragma unroll
      for (int i = 0; i < 4; ++i)
        af[i] = *(const bf16x8*)&As[p][(wm + i * 16 + l15) * 32 + sel];
      #pragma unroll
      for (int j = 0; j < 4; ++j)
        bfr[j] = *(const bf16x8*)&Bs[p][(wn + j * 16 + l15) * 32 + sel];
      #pragma unroll
      for (int i = 0; i < 4; ++i)
        #pragma unroll
        for (int j = 0; j < 4; ++j)
          acc[i][j] = __builtin_amdgcn_mfma_f32_16x16x32_bf16(af[i], bfr[j], acc[i][j], 0, 0, 0);
    }
  }

  const int row0 = by * 128 + wm + quad * 4;
  const int col0 = bx * 128 + wn + l15;
  float lmax = 0.f;
  #pragma unroll
  for (int i = 0; i < 4; ++i)
    #pragma unroll
    for (int j = 0; j < 4; ++j)
      #pragma unroll
      for (int r = 0; r < 4; ++r) {
        float v = acc[i][j][r];
        lmax = fmaxf(lmax, fabsf(v));
        Hexp[(size_t)(row0 + i * 16 + r) * 4096 + (col0 + j * 16)] = f2bf(v);
      }

  #pragma unroll
  for (int off = 32; off > 0; off >>= 1)
    lmax = fmaxf(lmax, __shfl_down(lmax, off));
  if (lane == 0) wredmax[wave] = lmax;
  __syncthreads();
  if (tid == 0) {
    float m = fmaxf(fmaxf(wredmax[0], wredmax[1]), fmaxf(wredmax[2], wredmax[3]));
    atomicMax(amax_bits, __float_as_uint(m));
  }
}

// ---------------- quantize Hexp [8192,4096] in place (16B accesses) ----------------
__global__ void quant_h_kernel(ushort* __restrict__ H,
                               const unsigned* __restrict__ amax_bits) {
  const float amax = fmaxf(__uint_as_float(*amax_bits), 1e-8f);
  const float scale = 127.f / amax;
  const int n8 = 8192 * 4096 / 8;  // uint4 chunks (contiguous array)
  for (int i = blockIdx.x * blockDim.x + threadIdx.x; i < n8;
       i += gridDim.x * blockDim.x) {
    uint4* p = (uint4*)H + i;
    uint4 a = *p;
    unsigned w[4] = {a.x, a.y, a.z, a.w};
    #pragma unroll
    for (int j = 0; j < 4; ++j) {
      float lo = bf2f((ushort)(w[j] & 0xFFFF));
      float hi = bf2f((ushort)(w[j] >> 16));
      lo = fminf(fmaxf(rintf(lo * scale), -128.f), 127.f) / scale;
      hi = fminf(fmaxf(rintf(hi * scale), -128.f), 127.f) / scale;
      w[j] = (unsigned)f2bf(lo) | ((unsigned)f2bf(hi) << 16);
    }
    *p = make_uint4(w[0], w[1], w[2], w[3]);
  }
}

// ---------------- GEMM2: out[8192,1024] = relu(Hq@Wq^T + xbf@G + b) ----------------
// Split-K: loop1 K=4096 (Hq, Wq B^T-layout), loop2 K=1024 (xbf, G symmetric).
// 512 blocks; XCD swizzle: each XCD owns 8 consecutive by row-tiles.
__global__ __launch_bounds__(256, 2) void gemm2_kernel(
    const ushort* __restrict__ Hq, const ushort* __restrict__ Wq,
    const ushort* __restrict__ Xb, const ushort* __restrict__ G,
    const float* __restrict__ bias, float* __restrict__ out) {
  __shared__ __align__(16) ushort As[2][128 * 32];
  __shared__ __align__(16) ushort Bs[2][128 * 32];

  const int l = blockIdx.x;
  const int xcd = l & 7;
  const int s = l >> 3;
  const int by = (xcd << 3) | (s >> 3);
  const int bx = s & 7;

  const int tid = threadIdx.x;
  const int lane = tid & 63, wave = tid >> 6;
  const int wm = (wave >> 1) << 6, wn = (wave & 1) << 6;
  const int l15 = lane & 15, quad = lane >> 4;
  const int sel = (quad ^ ((l15 >> 1) & 3)) * 8;        // read-side swizzle
  const int scs = ((tid & 3) ^ ((tid >> 3) & 3)) * 8;   // stage-side swizzle

  ushort* Asl0 = As[0] + tid * 8; ushort* Asl1 = As[1] + tid * 8;
  ushort* Bsl0 = Bs[0] + tid * 8; ushort* Bsl1 = Bs[1] + tid * 8;

  f32x4 acc[4][4];
  #pragma unroll
  for (int i = 0; i < 4; ++i)
    #pragma unroll
    for (int j = 0; j < 4; ++j) acc[i][j] = (f32x4){0.f, 0.f, 0.f, 0.f};

  // ---- loop 1: K=4096 over Hq / Wq (stride 4096) ----
  {
    const ushort* Ag = Hq + (size_t)(by * 128 + (tid >> 2)) * 4096 + scs;
    const ushort* Bg = Wq + (size_t)(bx * 128 + (tid >> 2)) * 4096 + scs;
    for (int k0 = 0; k0 < 4096; k0 += 64) {
      __syncthreads();
      gload16(Ag + k0, Asl0);
      gload16(Ag + (size_t)64 * 4096 + k0, Asl0 + 64 * 32);
      gload16(Bg + k0, Bsl0);
      gload16(Bg + (size_t)64 * 4096 + k0, Bsl0 + 64 * 32);
      gload16(Ag + k0 + 32, Asl1);
      gload16(Ag + (size_t)64 * 4096 + k0 + 32, Asl1 + 64 * 32);
      gload16(Bg + k0 + 32, Bsl1);
      gload16(Bg + (size_t)64 * 4096 + k0 + 32, Bsl1 + 64 * 32);
      __syncthreads();
      #pragma unroll
      for (int p = 0; p < 2; ++p) {
        bf16x8 af[4], bfr[4];
        #pragma unroll
        for (int i = 0; i < 4; ++i)
          af[i] = *(const bf16x8*)&As[p][(wm + i * 16 + l15) * 32 + sel];
        #pragma unroll
        for (int j = 0; j < 4; ++j)
          bfr[j] = *(const bf16x8*)&Bs[p][(wn + j * 16 + l15) * 32 + sel];
        #pragma unroll
        for (int i = 0; i < 4; ++i)
          #pragma unroll
          for (int j = 0; j < 4; ++j)
            acc[i][j] = __builtin_amdgcn_mfma_f32_16x16x32_bf16(af[i], bfr[j], acc[i][j], 0, 0, 0);
      }
    }
  }
  // ---- loop 2: K=1024 over xbf / G (stride 1024) ----
  {
    const ushort* Ag = Xb + (size_t)(by * 128 + (tid >> 2)) * 1024 + scs;
    const ushort* Bg = G + (size_t)(bx * 128 + (tid >> 2)) * 1024 + scs;
    for (int k0 = 0; k0 < 1024; k0 += 64) {
      __syncthreads();
      gload16(Ag + k0, Asl0);
      gload16(Ag + 64 * 1024 + k0, Asl0 + 64 * 32);
      gload16(Bg + k0, Bsl0);
      gload16(Bg + 64 * 1024 + k0, Bsl0 + 64 * 32);
      gload16(Ag + k0 + 32, Asl1);
      gload16(Ag + 64 * 1024 + k0 + 32, Asl1 + 64 * 32);
      gload16(Bg + k0 + 32, Bsl1);
      gload16(Bg + 64 * 1024 + k0 + 32, Bsl1 + 64 * 32);
      __syncthreads();
      #pragma unroll
      for (int p = 0; p < 2; ++p) {
        bf16x8 af[4], bfr[4];
        #pragma unroll
        for (int i = 0; i < 4; ++i)
          af[i] = *(const bf16x8*)&As[p][(wm + i * 16 + l15) * 32 + sel];
        #pragma unroll
        for (int j = 0; j < 4; ++j)
          bfr[j] = *(const bf16x8*)&Bs[p][(wn + j * 16 + l15) * 32 + sel];
        #pragma unroll
        for (int i = 0; i < 4; ++i)
          #pragma unroll
          for (int j = 0; j < 4; ++j)
            acc[i][j] = __builtin_amdgcn_mfma_f32_16x16x32_bf16(af[i], bfr[j], acc[i][j], 0, 0, 0);
      }
    }
  }

  const int row0 = by * 128 + wm + quad * 4;
  const int col0 = bx * 128 + wn + l15;
  #pragma unroll
  for (int i = 0; i < 4; ++i)
    #pragma unroll
    for (int j = 0; j < 4; ++j) {
      float bv = bias[col0 + j * 16];
      #pragma unroll
      for (int r = 0; r < 4; ++r) {
        float v = acc[i][j][r] + bv;
        v = fmaxf(v, 0.f);
        out[(size_t)(row0 + i * 16 + r) * 1024 + (col0 + j * 16)] = v;
      }
    }
}

extern "C" void kernel_launch(void* const* d_in, const int* in_sizes, int n_in,
                              void* d_out, int out_size, void* d_ws, size_t ws_size,
                              hipStream_t stream) {
  (void)in_sizes; (void)n_in; (void)out_size; (void)ws_size;
  const float* x = (const float*)d_in[0];   // [8192,1024]
  const float* W = (const float*)d_in[1];   // [1024,8192]
  const float* b = (const float*)d_in[2];   // [1024]

  char* ws = (char*)d_ws;
  unsigned* scal = (unsigned*)ws;                      // [1]=amax_h, [16..2064)=amax_x slots
  ushort* xq   = (ushort*)(ws + 16384);                // 16 MB [8192,1024]
  ushort* xbf  = xq   + (size_t)8192 * 1024;           // 16 MB [8192,1024]
  ushort* Wq   = xbf  + (size_t)8192 * 1024;           //  8 MB [1024,4096]
  ushort* WqT  = Wq   + (size_t)1024 * 4096;           //  8 MB [4096,1024]
  ushort* Wcb  = WqT  + (size_t)4096 * 1024;           //  8 MB [1024,4096]
  ushort* G    = Wcb  + (size_t)1024 * 4096;           //  2 MB [1024,1024]
  ushort* Hexp = G    + (size_t)1024 * 1024;           // 64 MB [8192,4096]

  // L1: W-quant+transpose (1024 blocks) | Wc-cast (4096) | amax_x slots (2048)
  prep_wa_kernel<<<7168, 256, 0, stream>>>(W, (const float4*)x, Wq, WqT, Wcb, scal);
  // L2: prep_x (2048) — reduces amax_x slots itself
  prep_x_kernel<<<2048, 256, 0, stream>>>((const float4*)x,
                                          (const float*)(scal + 16),
                                          (uint4*)xq, (uint4*)xbf);
  // L3: G-GEMM (64 blocks, 128x128 tiles) | gemm1 (2048)
  gemm1_kernel<<<2112, 256, 0, stream>>>(Wcb, G, xq, WqT, Hexp, scal + 1);
  quant_h_kernel<<<4096, 256, 0, stream>>>(Hexp, scal + 1);
  gemm2_kernel<<<512, 256, 0, stream>>>(Hexp, Wq, xbf, G, b, (float*)d_out);
}